// Round 11
// baseline (61.383 us; speedup 1.0000x reference)
//
#include <hip/hip_runtime.h>
#include <hip/hip_fp16.h>
#include <math.h>

#define NPIXD 1024
#define GD    2048
#define NCHAND 4
#define NVISD 200000
#define KXROWS 408     // kx rows computed/stored (gather needs <=401; clamped)
#define YPACK  832     // centered packing: pos = y_signed + 416
#define FINP   1024    // Fin row pitch (half2 slots)
#define IDX(i) ((i) + ((i) >> 4))   // LDS pad
#define RSQ2   0.70710678118654752f

#define FH_SCALE   1048576.0f       // 2^20 net scale of FhH
#define FH_ISCALE  (1.0f / 1048576.0f)
#define FIN_SCALE  4194304.0f       // 2^22 scale of Fin (half2)
#define FIN_TO_FH  0.25f            // 2^22 -> 2^20
#define FIN_TO_IM  (1.0f / 4194304.0f)

static constexpr double PI_D = 3.14159265358979323846;
static constexpr float SCALE_F = (float)(1000.0 * 0.005 * PI_D / (180.0 * 3600.0) * 2048.0);
static constexpr float BETA_F  = (float)(2.34 * 6.0);

// inline apodization: for i in [0,1024), arg = beta^2 - (pi*6*(i-512)/2048)^2 >= 173 > 0
__device__ __forceinline__ float apodf(int i) {
    float n  = (float)(i - 512) * (1.0f / 2048.0f);
    float t  = (float)(PI_D * 6.0) * n;
    float arg = BETA_F * BETA_F - t * t;
    float sq = sqrtf(arg);
    float e  = __expf(sq);
    return sq * 2.0f / (e - 1.0f / e);     // sq / sinh(sq)
}

__device__ __forceinline__ float2 cadd(float2 a, float2 b){ return make_float2(a.x+b.x, a.y+b.y); }
__device__ __forceinline__ float2 csub(float2 a, float2 b){ return make_float2(a.x-b.x, a.y-b.y); }
__device__ __forceinline__ float2 cmulf(float2 a, float2 b){ return make_float2(a.x*b.x - a.y*b.y, a.x*b.y + a.y*b.x); }
__device__ __forceinline__ float2 cnegi(float2 a){ return make_float2(a.y, -a.x); }

// twiddle exp(-i*pi*e/1024); e integer-valued <= 1785 (fp32-exact)
__device__ __forceinline__ float2 twf(float e) {
    float s, c;
    __sincosf(e * (float)(-PI_D / 1024.0), &s, &c);
    return make_float2(c, s);
}

// DFT8 with x2..x5 == 0
__device__ __forceinline__ void dft8_sparse(float2 x0, float2 x1, float2 x6, float2 x7,
                                            float2 y[8]) {
    float2 u0 = cadd(x0,x6), u1 = csub(x0,x6), u2 = cadd(x1,x7), u3 = cnegi(csub(x1,x7));
    y[0]=cadd(u0,u2); y[2]=cadd(u1,u3); y[4]=csub(u0,u2); y[6]=csub(u1,u3);
    float2 o0 = x0;
    float2 o1 = make_float2(RSQ2*(x1.x + x1.y), RSQ2*(x1.y - x1.x));
    float2 o2 = make_float2(-x6.y, x6.x);
    float2 o3 = make_float2(RSQ2*(x7.x - x7.y), RSQ2*(x7.y + x7.x));
    float2 v0 = cadd(o0,o2), v1 = csub(o0,o2), v2 = cadd(o1,o3), v3 = cnegi(csub(o1,o3));
    y[1]=cadd(v0,v2); y[3]=cadd(v1,v3); y[5]=csub(v0,v2); y[7]=csub(v1,v3);
}

__device__ __forceinline__ void dft8_full(const float2 x[8], float2 y[8]) {
    float2 e0=cadd(x[0],x[4]), e1=cadd(x[1],x[5]), e2=cadd(x[2],x[6]), e3=cadd(x[3],x[7]);
    float2 o0=csub(x[0],x[4]), o1=csub(x[1],x[5]), o2=csub(x[2],x[6]), o3=csub(x[3],x[7]);
    o1 = make_float2(RSQ2*(o1.x + o1.y), RSQ2*(o1.y - o1.x));
    o2 = cnegi(o2);
    o3 = make_float2(RSQ2*(o3.y - o3.x), -RSQ2*(o3.x + o3.y));
    float2 u0=cadd(e0,e2), u1=csub(e0,e2), u2=cadd(e1,e3), u3=cnegi(csub(e1,e3));
    y[0]=cadd(u0,u2); y[2]=cadd(u1,u3); y[4]=csub(u0,u2); y[6]=csub(u1,u3);
    float2 v0=cadd(o0,o2), v1=csub(o0,o2), v2=cadd(o1,o3), v3=cnegi(csub(o1,o3));
    y[1]=cadd(v0,v2); y[3]=cadd(v1,v3); y[5]=csub(v0,v2); y[7]=csub(v1,v3);
}

// stage 0 (m=1, pm=j): sparse DFT8 from registers -> dst
__device__ __forceinline__ void stage0_st(float2 x0, float2 x1, float2 x6, float2 x7,
                                          float2* __restrict__ dst) {
    int j = (int)threadIdx.x;
    float2 y[8];
    dft8_sparse(x0, x1, x6, x7, y);
    dst[IDX(8 * j)] = y[0];
    #pragma unroll
    for (int t = 1; t < 8; ++t)
        dst[IDX(8 * j + t)] = cmulf(twf((float)(t * j)), y[t]);
}

// radix-8 Stockham stage src -> dst (no internal barrier)
__device__ __forceinline__ void r8_st(const float2* __restrict__ src, float2* __restrict__ dst,
                                      int m) {
    int j = (int)threadIdx.x;
    float2 x[8], y[8];
    #pragma unroll
    for (int k = 0; k < 8; ++k) x[k] = src[IDX(j + 256 * k)];
    dft8_full(x, y);
    int pm = j & ~(m - 1);
    int base = 7 * pm + j;
    dst[IDX(base)] = y[0];
    #pragma unroll
    for (int t = 1; t < 8; ++t)
        dst[IDX(base + t * m)] = cmulf(twf((float)(t * pm)), y[t]);
}

// final radix-4 src -> dst, PRUNED: only t=0 (j) and t=3 (j+1536) written
__device__ __forceinline__ void r4_final_st(const float2* __restrict__ src,
                                            float2* __restrict__ dst) {
    #pragma unroll
    for (int h = 0; h < 2; ++h) {
        int jj = (int)threadIdx.x + h * 256;
        float2 a = src[IDX(jj)], b = src[IDX(jj + 512)];
        float2 cc = src[IDX(jj + 1024)], d = src[IDX(jj + 1536)];
        float2 u0 = cadd(a,cc), u1 = csub(a,cc), u2 = cadd(b,d), u3 = cnegi(csub(b,d));
        dst[IDX(jj)]        = cadd(u0,u2);   // t=0
        dst[IDX(jj + 1536)] = csub(u1,u3);   // t=3
    }
}

// in-place radix-8 (read-all, barrier, write-all) -- used by fft_cols (smaller LDS)
__device__ __forceinline__ void r8_ip(float2* __restrict__ buf, int m) {
    int j = (int)threadIdx.x;
    float2 x[8];
    #pragma unroll
    for (int k = 0; k < 8; ++k) x[k] = buf[IDX(j + 256 * k)];
    __syncthreads();
    float2 y[8];
    dft8_full(x, y);
    int pm = j & ~(m - 1);
    int base = 7 * pm + j;
    buf[IDX(base)] = y[0];
    #pragma unroll
    for (int t = 1; t < 8; ++t)
        buf[IDX(base + t * m)] = cmulf(twf((float)(t * pm)), y[t]);
}

__device__ __forceinline__ void r4_final_ip(float2* __restrict__ buf) {
    int j = (int)threadIdx.x;
    float2 v[8];
    #pragma unroll
    for (int h = 0; h < 2; ++h) {
        int jj = j + h * 256;
        v[h*4+0] = buf[IDX(jj)];
        v[h*4+1] = buf[IDX(jj + 512)];
        v[h*4+2] = buf[IDX(jj + 1024)];
        v[h*4+3] = buf[IDX(jj + 1536)];
    }
    __syncthreads();
    #pragma unroll
    for (int h = 0; h < 2; ++h) {
        int jj = j + h * 256;
        float2 a = v[h*4], b = v[h*4+1], cc = v[h*4+2], d = v[h*4+3];
        float2 u0 = cadd(a,cc), u1 = csub(a,cc), u2 = cadd(b,d), u3 = cnegi(csub(b,d));
        buf[IDX(jj)]        = cadd(u0,u2);
        buf[IDX(jj + 1536)] = csub(u1,u3);
    }
}

// ---------------- pass 1 FUSED, double-buffered: 4 row-pairs/block, half2 Fin ----------
__global__ __launch_bounds__(256) void fft_rows_fused(const float* __restrict__ img,
                                                      unsigned int* __restrict__ FinU) {
    __shared__ float2 bufA[2176];
    __shared__ float2 bufB[2176];
    __shared__ unsigned int stg[KXROWS * 9];   // half2 bits; pitch 9 (conflict-free)
    int j  = (int)threadIdx.x;
    int bx = (int)blockIdx.x;                  // 0..127
    int c  = (int)blockIdx.y;
    int w  = (bx & 7) * 16 + (bx >> 3);        // bijective: 128 = 8*16
    int y0 = w * 4;
    float a0 = apodf(j + 512), a1 = apodf(j + 768), a6 = apodf(j), a7 = apodf(j + 256);
    float ay[8];
    #pragma unroll
    for (int p = 0; p < 4; ++p) { ay[p] = apodf(y0 + p); ay[4 + p] = apodf(y0 + 512 + p); }
    float p1[4], p2[4];
    {
        const float* r1 = img + ((size_t)c * NPIXD + y0) * NPIXD;
        const float* r2 = img + ((size_t)c * NPIXD + y0 + 512) * NPIXD;
        p1[0]=r1[j+512]; p1[1]=r1[j+768]; p1[2]=r1[j]; p1[3]=r1[j+256];
        p2[0]=r2[j+512]; p2[1]=r2[j+768]; p2[2]=r2[j]; p2[3]=r2[j+256];
    }
    #pragma unroll
    for (int p = 0; p < 4; ++p) {
        float ay1 = ay[p], ay2 = ay[4 + p];
        float2 x0 = make_float2(p1[0]*a0*ay1, p2[0]*a0*ay2);
        float2 x1 = make_float2(p1[1]*a1*ay1, p2[1]*a1*ay2);
        float2 x6 = make_float2(p1[2]*a6*ay1, p2[2]*a6*ay2);
        float2 x7 = make_float2(p1[3]*a7*ay1, p2[3]*a7*ay2);
        if (p < 3) {
            const float* q1 = img + ((size_t)c * NPIXD + y0 + p + 1) * NPIXD;
            const float* q2 = img + ((size_t)c * NPIXD + y0 + p + 513) * NPIXD;
            p1[0]=q1[j+512]; p1[1]=q1[j+768]; p1[2]=q1[j]; p1[3]=q1[j+256];
            p2[0]=q2[j+512]; p2[1]=q2[j+768]; p2[2]=q2[j]; p2[3]=q2[j+256];
        }
        // dbuf schedule: A free here (prev r4 readers synced), B freed by stage0-sync
        stage0_st(x0, x1, x6, x7, bufA);
        __syncthreads();
        r8_st(bufA, bufB, 8);
        __syncthreads();
        r8_st(bufB, bufA, 64);
        __syncthreads();
        r4_final_st(bufA, bufB);
        __syncthreads();
        // Hermitian unpair epilogue -> stage (half2 bits, scaled 2^22)
        #pragma unroll
        for (int t = 0; t < 2; ++t) {
            int kx = j + t * 256;
            if (kx < KXROWS) {
                float2 Z  = bufB[IDX(kx)];
                float2 Zm = bufB[IDX((GD - kx) & (GD - 1))];
                __half2 h1 = __floats2half2_rn(0.5f*(Z.x+Zm.x)*FIN_SCALE, 0.5f*(Z.y-Zm.y)*FIN_SCALE);
                __half2 h2 = __floats2half2_rn(0.5f*(Z.y+Zm.y)*FIN_SCALE, 0.5f*(Zm.x-Z.x)*FIN_SCALE);
                stg[kx * 9 + p]     = *reinterpret_cast<unsigned int*>(&h1);
                stg[kx * 9 + 4 + p] = *reinterpret_cast<unsigned int*>(&h2);
            }
        }
    }
    __syncthreads();
    // write-out: 816 chunks of 16B (4 half2): chunk m -> (kx = m>>1, half = m&1)
    #pragma unroll
    for (int k = 0; k < 4; ++k) {
        int m = j + 256 * k;
        if (m < 2 * KXROWS) {
            int kx = m >> 1, h = m & 1;
            unsigned int* dst = FinU + ((size_t)c * KXROWS + kx) * FINP + y0 + h * 512;
            const unsigned int* s = &stg[kx * 9 + h * 4];
            *reinterpret_cast<uint4*>(dst) = make_uint4(s[0], s[1], s[2], s[3]);
        }
    }
}

// ---------------- pass 2: col FFTs from half2 Fin; Re -> half4 interleaved --------------
__global__ __launch_bounds__(256) void fft_cols(const unsigned int* __restrict__ FinU,
                                                __half* __restrict__ FhH,
                                                float* __restrict__ FhIm,
                                                int writeIm) {
    __shared__ float2 buf[2176];
    int j = (int)threadIdx.x;
    int kx = blockIdx.x, c = blockIdx.y;
    const unsigned int* inr = FinU + ((size_t)c * KXROWS + kx) * FINP;
    unsigned int u0 = inr[j + 512], u1 = inr[j + 768], u6 = inr[j], u7 = inr[j + 256];
    float2 x0 = __half22float2(*reinterpret_cast<__half2*>(&u0));
    float2 x1 = __half22float2(*reinterpret_cast<__half2*>(&u1));
    float2 x6 = __half22float2(*reinterpret_cast<__half2*>(&u6));
    float2 x7 = __half22float2(*reinterpret_cast<__half2*>(&u7));
    stage0_st(x0, x1, x6, x7, buf);
    __syncthreads();
    r8_ip(buf, 8);
    __syncthreads();
    r8_ip(buf, 64);
    __syncthreads();
    r4_final_ip(buf);
    __syncthreads();
    __half* basep = FhH + ((size_t)kx * YPACK) * NCHAND + c;
    float*  imb   = FhIm + ((size_t)c * KXROWS + kx) * YPACK;
    for (int n = j; n < GD; n += 256) {
        int pos = -1;
        if (n < 416)         pos = n + 416;
        else if (n >= 1632)  pos = n - 1632;
        if (pos >= 0) {
            float2 z = buf[IDX(n)];
            basep[(size_t)pos * NCHAND] = __float2half_rn(z.x * FIN_TO_FH);
            if (writeIm) imb[pos] = z.y * FIN_TO_IM;
        }
    }
}

// ---------------- Kaiser-Bessel weights ----------------
__device__ __forceinline__ float i0f(float x) {
    float ax = fabsf(x);
    if (ax <= 3.75f) {
        float ts = ax / 3.75f; ts *= ts;
        return 1.0f + ts * (3.5156229f + ts * (3.0899424f + ts * (1.2067492f +
                     ts * (0.2659732f + ts * (0.0360768f + ts * 0.0045813f)))));
    } else {
        float t = 3.75f / ax;
        return expf(ax) / sqrtf(ax) *
               (0.39894228f + t * (0.01328592f + t * (0.00225319f + t * (-0.00157565f +
                t * (0.00916281f + t * (-0.02057706f + t * (0.02635537f +
                t * (-0.01647633f + t * 0.00392377f))))))));
    }
}

__device__ __forceinline__ float kbwf(float dist) {
    float r = dist * (2.0f / 6.0f);
    float s = 1.0f - r * r;
    if (s <= 0.0f) return 0.0f;
    return i0f(BETA_F * sqrtf(s)) * (1.0f / 6.0f);
}

// ---------------- gather: 4 thr/vis (thread r owns float4-quad q=r), shfl reduce -------
__global__ __launch_bounds__(256) void gather7(const float* __restrict__ uu,
                                               const float* __restrict__ vv,
                                               const float4* __restrict__ FhH4,
                                               const float* __restrict__ FhIm,
                                               float* __restrict__ out,
                                               int out_elems, int complexOut) {
    int tid = (int)threadIdx.x;
    int v = tid >> 2, r = tid & 3;
    int gv = blockIdx.x * 64 + v;
    if (gv >= NVISD) return;
    float tx = uu[gv] * SCALE_F;
    float ty = vv[gv] * SCALE_F;
    float fxf = floorf(tx), fyf = floorf(ty);
    int fxi = (int)fxf, fyi = (int)fyf;

    float wx[3]; int kxr[3]; int cjr[3];
    #pragma unroll
    for (int bb = 0; bb < 3; ++bb) {
        // kx taps split by parity below is NOT used; all threads compute all 6 wx? no:
        // we need all 6 kx taps; each thread handles quads of ALL 6 taps? Too many loads.
        // Layout: 6 kx-taps x 4 quads = 24 loads / 4 threads = 6 each: thread r does
        // taps {r&1? odd:even}? Simpler: 3 taps per (r>>1), quads (r&1)*2..+1.
        int b = (r >> 1) * 3 + bb;             // r in {0,1}: taps 0..2 ; r in {2,3}: taps 3..5
        int o = b - 2;
        wx[bb] = kbwf(tx - fxf - (float)o);
        int ix = (fxi + o) & (GD - 1);
        int cj = (ix > 1024) ? 1 : 0;
        int kx = cj ? (GD - ix) : ix;
        kxr[bb] = min(kx, KXROWS - 1);
        cjr[bb] = cj;
    }
    float wy[6];
    #pragma unroll
    for (int t = 0; t < 6; ++t) wy[t] = kbwf(ty - fyf - (float)(t - 2));

    int p0n = fyi + 414, p0c = 413 - fyi;
    p0n = min(max(p0n, 0), YPACK - 6);
    p0c = min(max(p0c, 0), YPACK - 6);
    int dn = p0n & 1, dc = p0c & 1;
    int f0n = (p0n - dn) >> 1, f0c = (p0c - dc) >> 1;
    float wn8[8], wc8[8];
    #pragma unroll
    for (int w = 0; w < 8; ++w) {
        int tn = w - dn; wn8[w] = (tn >= 0 && tn < 6) ? wy[tn] : 0.0f;
        int tc = w - dc; wc8[w] = (tc >= 0 && tc < 6) ? wy[5 - tc] : 0.0f;
    }

    int q0 = (r & 1) * 2;                      // quads {0,1} or {2,3}
    float s0 = 0.0f, s1 = 0.0f, s2 = 0.0f, s3 = 0.0f;
    #pragma unroll
    for (int bb = 0; bb < 3; ++bb) {
        const float4* rp = FhH4 + (size_t)kxr[bb] * (YPACK / 2);
        bool cj = cjr[bb] != 0;
        int f0 = cj ? f0c : f0n;
        float wxb = wx[bb];
        #pragma unroll
        for (int qq = 0; qq < 2; ++qq) {
            int q = q0 + qq;
            float4 Q = rp[f0 + q];
            float w0 = wxb * (cj ? wc8[2 * q]     : wn8[2 * q]);
            float w1 = wxb * (cj ? wc8[2 * q + 1] : wn8[2 * q + 1]);
            float2 fa = __half22float2(*reinterpret_cast<const __half2*>(&Q.x));
            float2 fb = __half22float2(*reinterpret_cast<const __half2*>(&Q.y));
            float2 fc = __half22float2(*reinterpret_cast<const __half2*>(&Q.z));
            float2 fd = __half22float2(*reinterpret_cast<const __half2*>(&Q.w));
            s0 = fmaf(w0, fa.x, fmaf(w1, fc.x, s0));
            s1 = fmaf(w0, fa.y, fmaf(w1, fc.y, s1));
            s2 = fmaf(w0, fb.x, fmaf(w1, fd.x, s2));
            s3 = fmaf(w0, fb.y, fmaf(w1, fd.y, s3));
        }
    }
    s0 += __shfl_xor(s0, 1); s0 += __shfl_xor(s0, 2);
    s1 += __shfl_xor(s1, 1); s1 += __shfl_xor(s1, 2);
    s2 += __shfl_xor(s2, 1); s2 += __shfl_xor(s2, 2);
    s3 += __shfl_xor(s3, 1); s3 += __shfl_xor(s3, 2);

    if (!complexOut) {
        if (r == 0 && (size_t)3 * NVISD + gv < (size_t)out_elems) {
            out[0 * NVISD + gv] = s0 * FH_ISCALE;
            out[1 * NVISD + gv] = s1 * FH_ISCALE;
            out[2 * NVISD + gv] = s2 * FH_ISCALE;
            out[3 * NVISD + gv] = s3 * FH_ISCALE;
        }
    } else {
        float sr[4] = {s0, s1, s2, s3};
        #pragma unroll
        for (int c = 0; c < NCHAND; ++c) {
            float sy = 0.0f;
            const float* baseI = FhIm + (size_t)c * KXROWS * YPACK;
            if (r < 2) {   // threads 0,1 each do their 3 taps, full y windows
                #pragma unroll
                for (int bb = 0; bb < 3; ++bb) {
                    const float* rp = baseI + (size_t)kxr[bb] * YPACK;
                    bool cj = cjr[bb] != 0;
                    float wxb = wx[bb];
                    #pragma unroll
                    for (int a = 0; a < 6; ++a) {
                        int yv = fyi + (a - 2);
                        int pos = cj ? (416 - yv) : (yv + 416);
                        pos = min(max(pos, 0), YPACK - 1);
                        float w = wxb * wy[a];
                        sy = fmaf(cj ? -w : w, rp[pos], sy);
                    }
                }
            }
            // note: threads 0,1 hold taps 0..2; threads 2,3 hold taps 3..5 -> need r in {0,2}
            // handled: r<2 covers taps 0..2 only. Use r==0 and r==2 instead:
            sy = (r == 0 || r == 2) ? sy : 0.0f;
            sy += __shfl_xor(sy, 1); sy += __shfl_xor(sy, 2);
            size_t oidx = (size_t)c * NVISD + gv;
            if (r == 0 && 2 * oidx + 1 < (size_t)out_elems) {
                out[2 * oidx] = sr[c] * FH_ISCALE;
                out[2 * oidx + 1] = sy;
            }
        }
    }
}

extern "C" void kernel_launch(void* const* d_in, const int* in_sizes, int n_in,
                              void* d_out, int out_size, void* d_ws, size_t ws_size,
                              hipStream_t stream) {
    (void)in_sizes; (void)n_in;
    const float* img = (const float*)d_in[0];
    const float* uu  = (const float*)d_in[1];
    const float* vv  = (const float*)d_in[2];

    const size_t finBytes  = (size_t)NCHAND * KXROWS * FINP * sizeof(unsigned int); // 6.68 MB
    const size_t fhhBytes  = (size_t)KXROWS * YPACK * NCHAND * sizeof(__half);      // 2.72 MB
    const size_t fhimBytes = (size_t)NCHAND * KXROWS * YPACK * sizeof(float);       // 5.43 MB
    const size_t need = finBytes + fhhBytes + fhimBytes;                            // ~14.8 MB

    char* ws = (char*)d_ws;
    unsigned int* FinU = (unsigned int*)ws;
    __half* FhH  = (__half*)(ws + finBytes);
    float*  FhIm = (float*)(ws + finBytes + fhhBytes);

    if (ws_size < need) return;  // diagnostic guard (ws ~268MB observed r7)

    int complexOut = (out_size >= 2 * NCHAND * NVISD) ? 1 : 0;

    fft_rows_fused<<<dim3(128, NCHAND), dim3(256), 0, stream>>>(img, FinU);
    fft_cols<<<dim3(KXROWS, NCHAND), dim3(256), 0, stream>>>(FinU, FhH, FhIm, complexOut);
    gather7<<<dim3((NVISD + 63) / 64), dim3(256), 0, stream>>>(
        uu, vv, (const float4*)FhH, FhIm, (float*)d_out, out_size, complexOut);
}

// Round 12
// 50.267 us; speedup vs baseline: 1.2212x; 1.2212x over previous
//
#include <hip/hip_runtime.h>
#include <hip/hip_fp16.h>
#include <math.h>

#define NPIXD 1024
#define GD    2048
#define NCHAND 4
#define NVISD 200000
#define KXROWS 408     // kx rows computed/stored (gather needs <=401; clamped)
#define YPACK  832     // centered packing: pos = y_signed + 416
#define FINP   1024    // Fin row pitch (half2 slots)
#define IDX(i) ((i) + ((i) >> 4))   // LDS pad
#define RSQ2   0.70710678118654752f

#define FH_SCALE   1048576.0f       // 2^20 net scale of FhH
#define FH_ISCALE  (1.0f / 1048576.0f)
#define FIN_SCALE  4194304.0f       // 2^22 scale of Fin (half2)
#define FIN_TO_FH  0.25f            // 2^22 -> 2^20
#define FIN_TO_IM  (1.0f / 4194304.0f)

static constexpr double PI_D = 3.14159265358979323846;
static constexpr float SCALE_F = (float)(1000.0 * 0.005 * PI_D / (180.0 * 3600.0) * 2048.0);
static constexpr float BETA_F  = (float)(2.34 * 6.0);

// inline apodization: for i in [0,1024), arg = beta^2 - (pi*6*(i-512)/2048)^2 >= 173 > 0
__device__ __forceinline__ float apodf(int i) {
    float n  = (float)(i - 512) * (1.0f / 2048.0f);
    float t  = (float)(PI_D * 6.0) * n;
    float arg = BETA_F * BETA_F - t * t;
    float sq = sqrtf(arg);
    float e  = __expf(sq);
    return sq * 2.0f / (e - 1.0f / e);     // sq / sinh(sq)
}

__device__ __forceinline__ float2 cadd(float2 a, float2 b){ return make_float2(a.x+b.x, a.y+b.y); }
__device__ __forceinline__ float2 csub(float2 a, float2 b){ return make_float2(a.x-b.x, a.y-b.y); }
__device__ __forceinline__ float2 cmulf(float2 a, float2 b){ return make_float2(a.x*b.x - a.y*b.y, a.x*b.y + a.y*b.x); }
__device__ __forceinline__ float2 cnegi(float2 a){ return make_float2(a.y, -a.x); }

// twiddle exp(-i*pi*e/1024); e integer-valued <= 1785 (fp32-exact)
__device__ __forceinline__ float2 twf(float e) {
    float s, c;
    __sincosf(e * (float)(-PI_D / 1024.0), &s, &c);
    return make_float2(c, s);
}

// DFT8 with x2..x5 == 0
__device__ __forceinline__ void dft8_sparse(float2 x0, float2 x1, float2 x6, float2 x7,
                                            float2 y[8]) {
    float2 u0 = cadd(x0,x6), u1 = csub(x0,x6), u2 = cadd(x1,x7), u3 = cnegi(csub(x1,x7));
    y[0]=cadd(u0,u2); y[2]=cadd(u1,u3); y[4]=csub(u0,u2); y[6]=csub(u1,u3);
    float2 o0 = x0;
    float2 o1 = make_float2(RSQ2*(x1.x + x1.y), RSQ2*(x1.y - x1.x));
    float2 o2 = make_float2(-x6.y, x6.x);
    float2 o3 = make_float2(RSQ2*(x7.x - x7.y), RSQ2*(x7.y + x7.x));
    float2 v0 = cadd(o0,o2), v1 = csub(o0,o2), v2 = cadd(o1,o3), v3 = cnegi(csub(o1,o3));
    y[1]=cadd(v0,v2); y[3]=cadd(v1,v3); y[5]=csub(v0,v2); y[7]=csub(v1,v3);
}

__device__ __forceinline__ void dft8_full(const float2 x[8], float2 y[8]) {
    float2 e0=cadd(x[0],x[4]), e1=cadd(x[1],x[5]), e2=cadd(x[2],x[6]), e3=cadd(x[3],x[7]);
    float2 o0=csub(x[0],x[4]), o1=csub(x[1],x[5]), o2=csub(x[2],x[6]), o3=csub(x[3],x[7]);
    o1 = make_float2(RSQ2*(o1.x + o1.y), RSQ2*(o1.y - o1.x));
    o2 = cnegi(o2);
    o3 = make_float2(RSQ2*(o3.y - o3.x), -RSQ2*(o3.x + o3.y));
    float2 u0=cadd(e0,e2), u1=csub(e0,e2), u2=cadd(e1,e3), u3=cnegi(csub(e1,e3));
    y[0]=cadd(u0,u2); y[2]=cadd(u1,u3); y[4]=csub(u0,u2); y[6]=csub(u1,u3);
    float2 v0=cadd(o0,o2), v1=csub(o0,o2), v2=cadd(o1,o3), v3=cnegi(csub(o1,o3));
    y[1]=cadd(v0,v2); y[3]=cadd(v1,v3); y[5]=csub(v0,v2); y[7]=csub(v1,v3);
}

// stage 0 (m=1, pm=j): sparse DFT8 from registers -> buf
__device__ __forceinline__ void stage0_ip(float2 x0, float2 x1, float2 x6, float2 x7,
                                          float2* __restrict__ buf) {
    int j = (int)threadIdx.x;
    float2 y[8];
    dft8_sparse(x0, x1, x6, x7, y);
    buf[IDX(8 * j)] = y[0];
    #pragma unroll
    for (int t = 1; t < 8; ++t)
        buf[IDX(8 * j + t)] = cmulf(twf((float)(t * j)), y[t]);
}

// in-place radix-8 Stockham stage: read-all, barrier, write-all. m in {8, 64}
__device__ __forceinline__ void r8_ip(float2* __restrict__ buf, int m) {
    int j = (int)threadIdx.x;
    float2 x[8];
    #pragma unroll
    for (int k = 0; k < 8; ++k) x[k] = buf[IDX(j + 256 * k)];
    __syncthreads();
    float2 y[8];
    dft8_full(x, y);
    int pm = j & ~(m - 1);
    int base = 7 * pm + j;
    buf[IDX(base)] = y[0];
    #pragma unroll
    for (int t = 1; t < 8; ++t)
        buf[IDX(base + t * m)] = cmulf(twf((float)(t * pm)), y[t]);
}

// final radix-4 (m=512, twiddle-free), PRUNED: only t=0 (j) and t=3 (j+1536) written
__device__ __forceinline__ void r4_final_ip(float2* __restrict__ buf) {
    int j = (int)threadIdx.x;
    float2 v[8];
    #pragma unroll
    for (int h = 0; h < 2; ++h) {
        int jj = j + h * 256;
        v[h*4+0] = buf[IDX(jj)];
        v[h*4+1] = buf[IDX(jj + 512)];
        v[h*4+2] = buf[IDX(jj + 1024)];
        v[h*4+3] = buf[IDX(jj + 1536)];
    }
    __syncthreads();
    #pragma unroll
    for (int h = 0; h < 2; ++h) {
        int jj = j + h * 256;
        float2 a = v[h*4], b = v[h*4+1], cc = v[h*4+2], d = v[h*4+3];
        float2 u0 = cadd(a,cc), u1 = csub(a,cc), u2 = cadd(b,d), u3 = cnegi(csub(b,d));
        buf[IDX(jj)]        = cadd(u0,u2);   // t=0
        buf[IDX(jj + 1536)] = csub(u1,u3);   // t=3
    }
}

// ---------------- pass 1 FUSED (r10 schedule): 4 row-pairs/block, half2 Fin ------------
__global__ __launch_bounds__(256) void fft_rows_fused(const float* __restrict__ img,
                                                      unsigned int* __restrict__ FinU) {
    __shared__ float2 buf[2176];
    __shared__ unsigned int stg[KXROWS * 9];   // half2 bits; pitch 9 (conflict-free)
    int j  = (int)threadIdx.x;
    int bx = (int)blockIdx.x;                  // 0..127
    int c  = (int)blockIdx.y;
    int w  = (bx & 7) * 16 + (bx >> 3);        // bijective: 128 = 8*16
    int y0 = w * 4;
    float a0 = apodf(j + 512), a1 = apodf(j + 768), a6 = apodf(j), a7 = apodf(j + 256);
    float ay[8];
    #pragma unroll
    for (int p = 0; p < 4; ++p) { ay[p] = apodf(y0 + p); ay[4 + p] = apodf(y0 + 512 + p); }
    float p1[4], p2[4];
    {
        const float* r1 = img + ((size_t)c * NPIXD + y0) * NPIXD;
        const float* r2 = img + ((size_t)c * NPIXD + y0 + 512) * NPIXD;
        p1[0]=r1[j+512]; p1[1]=r1[j+768]; p1[2]=r1[j]; p1[3]=r1[j+256];
        p2[0]=r2[j+512]; p2[1]=r2[j+768]; p2[2]=r2[j]; p2[3]=r2[j+256];
    }
    #pragma unroll
    for (int p = 0; p < 4; ++p) {
        float ay1 = ay[p], ay2 = ay[4 + p];
        float2 x0 = make_float2(p1[0]*a0*ay1, p2[0]*a0*ay2);
        float2 x1 = make_float2(p1[1]*a1*ay1, p2[1]*a1*ay2);
        float2 x6 = make_float2(p1[2]*a6*ay1, p2[2]*a6*ay2);
        float2 x7 = make_float2(p1[3]*a7*ay1, p2[3]*a7*ay2);
        if (p < 3) {   // software prefetch of next pair
            const float* q1 = img + ((size_t)c * NPIXD + y0 + p + 1) * NPIXD;
            const float* q2 = img + ((size_t)c * NPIXD + y0 + p + 513) * NPIXD;
            p1[0]=q1[j+512]; p1[1]=q1[j+768]; p1[2]=q1[j]; p1[3]=q1[j+256];
            p2[0]=q2[j+512]; p2[1]=q2[j+768]; p2[2]=q2[j]; p2[3]=q2[j+256];
        }
        __syncthreads();                     // buf free (prev epilogue reads done)
        stage0_ip(x0, x1, x6, x7, buf);
        __syncthreads();
        r8_ip(buf, 8);
        __syncthreads();
        r8_ip(buf, 64);
        __syncthreads();
        r4_final_ip(buf);
        __syncthreads();
        // Hermitian unpair epilogue -> stage (half2 bits, scaled 2^22)
        #pragma unroll
        for (int t = 0; t < 2; ++t) {
            int kx = j + t * 256;
            if (kx < KXROWS) {
                float2 Z  = buf[IDX(kx)];
                float2 Zm = buf[IDX((GD - kx) & (GD - 1))];
                __half2 h1 = __floats2half2_rn(0.5f*(Z.x+Zm.x)*FIN_SCALE, 0.5f*(Z.y-Zm.y)*FIN_SCALE);
                __half2 h2 = __floats2half2_rn(0.5f*(Z.y+Zm.y)*FIN_SCALE, 0.5f*(Zm.x-Z.x)*FIN_SCALE);
                stg[kx * 9 + p]     = *reinterpret_cast<unsigned int*>(&h1);
                stg[kx * 9 + 4 + p] = *reinterpret_cast<unsigned int*>(&h2);
            }
        }
    }
    __syncthreads();
    // write-out: 816 chunks of 16B (4 half2): chunk m -> (kx = m>>1, half = m&1)
    #pragma unroll
    for (int k = 0; k < 4; ++k) {
        int m = j + 256 * k;
        if (m < 2 * KXROWS) {
            int kx = m >> 1, h = m & 1;
            unsigned int* dst = FinU + ((size_t)c * KXROWS + kx) * FINP + y0 + h * 512;
            const unsigned int* s = &stg[kx * 9 + h * 4];
            *reinterpret_cast<uint4*>(dst) = make_uint4(s[0], s[1], s[2], s[3]);
        }
    }
}

// ---------------- pass 2: col FFTs from half2 Fin; Re -> half4 interleaved --------------
__global__ __launch_bounds__(256) void fft_cols(const unsigned int* __restrict__ FinU,
                                                __half* __restrict__ FhH,
                                                float* __restrict__ FhIm,
                                                int writeIm) {
    __shared__ float2 buf[2176];
    int j = (int)threadIdx.x;
    int kx = blockIdx.x, c = blockIdx.y;
    const unsigned int* inr = FinU + ((size_t)c * KXROWS + kx) * FINP;
    unsigned int u0 = inr[j + 512], u1 = inr[j + 768], u6 = inr[j], u7 = inr[j + 256];
    float2 x0 = __half22float2(*reinterpret_cast<__half2*>(&u0));
    float2 x1 = __half22float2(*reinterpret_cast<__half2*>(&u1));
    float2 x6 = __half22float2(*reinterpret_cast<__half2*>(&u6));
    float2 x7 = __half22float2(*reinterpret_cast<__half2*>(&u7));
    stage0_ip(x0, x1, x6, x7, buf);
    __syncthreads();
    r8_ip(buf, 8);
    __syncthreads();
    r8_ip(buf, 64);
    __syncthreads();
    r4_final_ip(buf);
    __syncthreads();
    // centered packing: n<416 -> pos n+416 (y=n); n>=1632 -> pos n-1632 (y=n-2048)
    __half* basep = FhH + ((size_t)kx * YPACK) * NCHAND + c;
    float*  imb   = FhIm + ((size_t)c * KXROWS + kx) * YPACK;
    for (int n = j; n < GD; n += 256) {
        int pos = -1;
        if (n < 416)         pos = n + 416;
        else if (n >= 1632)  pos = n - 1632;
        if (pos >= 0) {
            float2 z = buf[IDX(n)];
            basep[(size_t)pos * NCHAND] = __float2half_rn(z.x * FIN_TO_FH);
            if (writeIm) imb[pos] = z.y * FIN_TO_IM;
        }
    }
}

// ---------------- Kaiser-Bessel weights ----------------
__device__ __forceinline__ float i0f(float x) {
    float ax = fabsf(x);
    if (ax <= 3.75f) {
        float ts = ax / 3.75f; ts *= ts;
        return 1.0f + ts * (3.5156229f + ts * (3.0899424f + ts * (1.2067492f +
                     ts * (0.2659732f + ts * (0.0360768f + ts * 0.0045813f)))));
    } else {
        float t = 3.75f / ax;
        return expf(ax) / sqrtf(ax) *
               (0.39894228f + t * (0.01328592f + t * (0.00225319f + t * (-0.00157565f +
                t * (0.00916281f + t * (-0.02057706f + t * (0.02635537f +
                t * (-0.01647633f + t * 0.00392377f))))))));
    }
}

__device__ __forceinline__ float kbwf(float dist) {
    float r = dist * (2.0f / 6.0f);
    float s = 1.0f - r * r;
    if (s <= 0.0f) return 0.0f;
    return i0f(BETA_F * sqrtf(s)) * (1.0f / 6.0f);
}

// ---------------- gather (r10 gather6): 2 thr/vis, 4x float4 per kx-tap ----------------
__global__ __launch_bounds__(256) void gather6(const float* __restrict__ uu,
                                               const float* __restrict__ vv,
                                               const float4* __restrict__ FhH4,
                                               const float* __restrict__ FhIm,
                                               float* __restrict__ out,
                                               int out_elems, int complexOut) {
    int tid = (int)threadIdx.x;
    int v = tid >> 1, r = tid & 1;
    int gv = blockIdx.x * 128 + v;
    if (gv >= NVISD) return;
    float tx = uu[gv] * SCALE_F;
    float ty = vv[gv] * SCALE_F;
    float fxf = floorf(tx), fyf = floorf(ty);
    int fxi = (int)fxf, fyi = (int)fyf;

    float wx[3]; int kxr[3]; int cjr[3];
    #pragma unroll
    for (int bb = 0; bb < 3; ++bb) {
        int b = r * 3 + bb, o = b - 2;
        wx[bb] = kbwf(tx - fxf - (float)o);
        int ix = (fxi + o) & (GD - 1);
        int cj = (ix > 1024) ? 1 : 0;
        int kx = cj ? (GD - ix) : ix;
        kxr[bb] = min(kx, KXROWS - 1);
        cjr[bb] = cj;
    }
    float wy[6];
    #pragma unroll
    for (int t = 0; t < 6; ++t) wy[t] = kbwf(ty - fyf - (float)(t - 2));

    int p0n = fyi + 414, p0c = 413 - fyi;
    p0n = min(max(p0n, 0), YPACK - 6);
    p0c = min(max(p0c, 0), YPACK - 6);
    int dn = p0n & 1, dc = p0c & 1;
    int f0n = (p0n - dn) >> 1, f0c = (p0c - dc) >> 1;
    float wn8[8], wc8[8];
    #pragma unroll
    for (int w = 0; w < 8; ++w) {
        int tn = w - dn; wn8[w] = (tn >= 0 && tn < 6) ? wy[tn] : 0.0f;
        int tc = w - dc; wc8[w] = (tc >= 0 && tc < 6) ? wy[5 - tc] : 0.0f;
    }

    float s0 = 0.0f, s1 = 0.0f, s2 = 0.0f, s3 = 0.0f;
    #pragma unroll
    for (int bb = 0; bb < 3; ++bb) {
        const float4* rp = FhH4 + (size_t)kxr[bb] * (YPACK / 2);
        bool cj = cjr[bb] != 0;
        int f0 = cj ? f0c : f0n;
        float wxb = wx[bb];
        #pragma unroll
        for (int q = 0; q < 4; ++q) {
            float4 Q = rp[f0 + q];
            float w0 = wxb * (cj ? wc8[2 * q]     : wn8[2 * q]);
            float w1 = wxb * (cj ? wc8[2 * q + 1] : wn8[2 * q + 1]);
            float2 fa = __half22float2(*reinterpret_cast<const __half2*>(&Q.x));
            float2 fb = __half22float2(*reinterpret_cast<const __half2*>(&Q.y));
            float2 fc = __half22float2(*reinterpret_cast<const __half2*>(&Q.z));
            float2 fd = __half22float2(*reinterpret_cast<const __half2*>(&Q.w));
            s0 = fmaf(w0, fa.x, fmaf(w1, fc.x, s0));
            s1 = fmaf(w0, fa.y, fmaf(w1, fc.y, s1));
            s2 = fmaf(w0, fb.x, fmaf(w1, fd.x, s2));
            s3 = fmaf(w0, fb.y, fmaf(w1, fd.y, s3));
        }
    }
    s0 += __shfl_xor(s0, 1);
    s1 += __shfl_xor(s1, 1);
    s2 += __shfl_xor(s2, 1);
    s3 += __shfl_xor(s3, 1);

    if (!complexOut) {
        if (r == 0 && (size_t)3 * NVISD + gv < (size_t)out_elems) {
            out[0 * NVISD + gv] = s0 * FH_ISCALE;
            out[1 * NVISD + gv] = s1 * FH_ISCALE;
            out[2 * NVISD + gv] = s2 * FH_ISCALE;
            out[3 * NVISD + gv] = s3 * FH_ISCALE;
        }
    } else {
        float sr[4] = {s0, s1, s2, s3};
        #pragma unroll
        for (int c = 0; c < NCHAND; ++c) {
            float sy = 0.0f;
            const float* baseI = FhIm + (size_t)c * KXROWS * YPACK;
            #pragma unroll
            for (int bb = 0; bb < 3; ++bb) {
                const float* rp = baseI + (size_t)kxr[bb] * YPACK;
                bool cj = cjr[bb] != 0;
                float wxb = wx[bb];
                #pragma unroll
                for (int a = 0; a < 6; ++a) {
                    int yv = fyi + (a - 2);
                    int pos = cj ? (416 - yv) : (yv + 416);
                    pos = min(max(pos, 0), YPACK - 1);
                    float w = wxb * wy[a];
                    sy = fmaf(cj ? -w : w, rp[pos], sy);
                }
            }
            sy += __shfl_xor(sy, 1);
            size_t oidx = (size_t)c * NVISD + gv;
            if (r == 0 && 2 * oidx + 1 < (size_t)out_elems) {
                out[2 * oidx] = sr[c] * FH_ISCALE;
                out[2 * oidx + 1] = sy;
            }
        }
    }
}

extern "C" void kernel_launch(void* const* d_in, const int* in_sizes, int n_in,
                              void* d_out, int out_size, void* d_ws, size_t ws_size,
                              hipStream_t stream) {
    (void)in_sizes; (void)n_in;
    const float* img = (const float*)d_in[0];
    const float* uu  = (const float*)d_in[1];
    const float* vv  = (const float*)d_in[2];

    const size_t finBytes  = (size_t)NCHAND * KXROWS * FINP * sizeof(unsigned int); // 6.68 MB
    const size_t fhhBytes  = (size_t)KXROWS * YPACK * NCHAND * sizeof(__half);      // 2.72 MB
    const size_t fhimBytes = (size_t)NCHAND * KXROWS * YPACK * sizeof(float);       // 5.43 MB
    const size_t need = finBytes + fhhBytes + fhimBytes;                            // ~14.8 MB

    char* ws = (char*)d_ws;
    unsigned int* FinU = (unsigned int*)ws;
    __half* FhH  = (__half*)(ws + finBytes);
    float*  FhIm = (float*)(ws + finBytes + fhhBytes);

    if (ws_size < need) return;  // diagnostic guard

    int complexOut = (out_size >= 2 * NCHAND * NVISD) ? 1 : 0;

    fft_rows_fused<<<dim3(128, NCHAND), dim3(256), 0, stream>>>(img, FinU);
    fft_cols<<<dim3(KXROWS, NCHAND), dim3(256), 0, stream>>>(FinU, FhH, FhIm, complexOut);
    gather6<<<dim3((NVISD + 127) / 128), dim3(256), 0, stream>>>(
        uu, vv, (const float4*)FhH, FhIm, (float*)d_out, out_size, complexOut);
}

// Round 13
// 49.105 us; speedup vs baseline: 1.2500x; 1.0237x over previous
//
#include <hip/hip_runtime.h>
#include <hip/hip_fp16.h>
#include <math.h>

#define NPIXD 1024
#define GD    2048
#define NCHAND 4
#define NVISD 200000
#define KXROWS 408     // kx rows computed/stored (gather needs <=401; clamped)
#define YPACK  832     // centered packing: pos = y_signed + 416
#define FINP   1024    // Fin row pitch (half2 slots)
#define IDX(i) ((i) + ((i) >> 4))   // LDS pad
#define RSQ2   0.70710678118654752f

#define FH_SCALE   1048576.0f       // 2^20 net scale of FhH
#define FH_ISCALE  (1.0f / 1048576.0f)
#define FIN_SCALE  4194304.0f       // 2^22 scale of Fin (half2)
#define FIN_TO_FH  0.25f            // 2^22 -> 2^20
#define FIN_TO_IM  (1.0f / 4194304.0f)

static constexpr double PI_D = 3.14159265358979323846;
static constexpr float SCALE_F = (float)(1000.0 * 0.005 * PI_D / (180.0 * 3600.0) * 2048.0);
static constexpr float BETA_F  = (float)(2.34 * 6.0);

// inline apodization: for i in [0,1024), arg = beta^2 - (pi*6*(i-512)/2048)^2 >= 173 > 0
__device__ __forceinline__ float apodf(int i) {
    float n  = (float)(i - 512) * (1.0f / 2048.0f);
    float t  = (float)(PI_D * 6.0) * n;
    float arg = BETA_F * BETA_F - t * t;
    float sq = sqrtf(arg);
    float e  = __expf(sq);
    return sq * 2.0f / (e - 1.0f / e);     // sq / sinh(sq)
}

__device__ __forceinline__ float2 cadd(float2 a, float2 b){ return make_float2(a.x+b.x, a.y+b.y); }
__device__ __forceinline__ float2 csub(float2 a, float2 b){ return make_float2(a.x-b.x, a.y-b.y); }
__device__ __forceinline__ float2 cmulf(float2 a, float2 b){ return make_float2(a.x*b.x - a.y*b.y, a.x*b.y + a.y*b.x); }
__device__ __forceinline__ float2 cnegi(float2 a){ return make_float2(a.y, -a.x); }

// twiddle exp(-i*pi*e/1024); e integer-valued <= 1785 (fp32-exact)
__device__ __forceinline__ float2 twf(float e) {
    float s, c;
    __sincosf(e * (float)(-PI_D / 1024.0), &s, &c);
    return make_float2(c, s);
}

// DFT8 with x2..x5 == 0
__device__ __forceinline__ void dft8_sparse(float2 x0, float2 x1, float2 x6, float2 x7,
                                            float2 y[8]) {
    float2 u0 = cadd(x0,x6), u1 = csub(x0,x6), u2 = cadd(x1,x7), u3 = cnegi(csub(x1,x7));
    y[0]=cadd(u0,u2); y[2]=cadd(u1,u3); y[4]=csub(u0,u2); y[6]=csub(u1,u3);
    float2 o0 = x0;
    float2 o1 = make_float2(RSQ2*(x1.x + x1.y), RSQ2*(x1.y - x1.x));
    float2 o2 = make_float2(-x6.y, x6.x);
    float2 o3 = make_float2(RSQ2*(x7.x - x7.y), RSQ2*(x7.y + x7.x));
    float2 v0 = cadd(o0,o2), v1 = csub(o0,o2), v2 = cadd(o1,o3), v3 = cnegi(csub(o1,o3));
    y[1]=cadd(v0,v2); y[3]=cadd(v1,v3); y[5]=csub(v0,v2); y[7]=csub(v1,v3);
}

__device__ __forceinline__ void dft8_full(const float2 x[8], float2 y[8]) {
    float2 e0=cadd(x[0],x[4]), e1=cadd(x[1],x[5]), e2=cadd(x[2],x[6]), e3=cadd(x[3],x[7]);
    float2 o0=csub(x[0],x[4]), o1=csub(x[1],x[5]), o2=csub(x[2],x[6]), o3=csub(x[3],x[7]);
    o1 = make_float2(RSQ2*(o1.x + o1.y), RSQ2*(o1.y - o1.x));
    o2 = cnegi(o2);
    o3 = make_float2(RSQ2*(o3.y - o3.x), -RSQ2*(o3.x + o3.y));
    float2 u0=cadd(e0,e2), u1=csub(e0,e2), u2=cadd(e1,e3), u3=cnegi(csub(e1,e3));
    y[0]=cadd(u0,u2); y[2]=cadd(u1,u3); y[4]=csub(u0,u2); y[6]=csub(u1,u3);
    float2 v0=cadd(o0,o2), v1=csub(o0,o2), v2=cadd(o1,o3), v3=cnegi(csub(o1,o3));
    y[1]=cadd(v0,v2); y[3]=cadd(v1,v3); y[5]=csub(v0,v2); y[7]=csub(v1,v3);
}

// stage 0 (m=1, pm=j): sparse DFT8 from registers -> buf
__device__ __forceinline__ void stage0_ip(float2 x0, float2 x1, float2 x6, float2 x7,
                                          float2* __restrict__ buf) {
    int j = (int)threadIdx.x;
    float2 y[8];
    dft8_sparse(x0, x1, x6, x7, y);
    buf[IDX(8 * j)] = y[0];
    #pragma unroll
    for (int t = 1; t < 8; ++t)
        buf[IDX(8 * j + t)] = cmulf(twf((float)(t * j)), y[t]);
}

// in-place radix-8 Stockham stage: read-all, barrier, write-all. m in {8, 64}
__device__ __forceinline__ void r8_ip(float2* __restrict__ buf, int m) {
    int j = (int)threadIdx.x;
    float2 x[8];
    #pragma unroll
    for (int k = 0; k < 8; ++k) x[k] = buf[IDX(j + 256 * k)];
    __syncthreads();
    float2 y[8];
    dft8_full(x, y);
    int pm = j & ~(m - 1);
    int base = 7 * pm + j;
    buf[IDX(base)] = y[0];
    #pragma unroll
    for (int t = 1; t < 8; ++t)
        buf[IDX(base + t * m)] = cmulf(twf((float)(t * pm)), y[t]);
}

// final radix-4 (m=512, twiddle-free), PRUNED: only t=0 (j) and t=3 (j+1536) written
__device__ __forceinline__ void r4_final_ip(float2* __restrict__ buf) {
    int j = (int)threadIdx.x;
    float2 v[8];
    #pragma unroll
    for (int h = 0; h < 2; ++h) {
        int jj = j + h * 256;
        v[h*4+0] = buf[IDX(jj)];
        v[h*4+1] = buf[IDX(jj + 512)];
        v[h*4+2] = buf[IDX(jj + 1024)];
        v[h*4+3] = buf[IDX(jj + 1536)];
    }
    __syncthreads();
    #pragma unroll
    for (int h = 0; h < 2; ++h) {
        int jj = j + h * 256;
        float2 a = v[h*4], b = v[h*4+1], cc = v[h*4+2], d = v[h*4+3];
        float2 u0 = cadd(a,cc), u1 = csub(a,cc), u2 = cadd(b,d), u3 = cnegi(csub(b,d));
        buf[IDX(jj)]        = cadd(u0,u2);   // t=0
        buf[IDX(jj + 1536)] = csub(u1,u3);   // t=3
    }
}

// ---------------- pass 1 FUSED: 2 CONSECUTIVE row-pairs/block (y0..y0+3), half2 Fin ----
// Pairing (y0,y0+1),(y0+2,y0+3): real-FFT pairing works for ANY two real rows, and
// consecutive coverage keeps the per-kx write one 16B chunk. 1024 blocks = 4/CU.
__global__ __launch_bounds__(256) void fft_rows_fused(const float* __restrict__ img,
                                                      unsigned int* __restrict__ FinU) {
    __shared__ float2 buf[2176];
    __shared__ unsigned int stg[KXROWS * 5];   // 4 half2 per kx + pad (pitch 5)
    int j  = (int)threadIdx.x;
    int bx = (int)blockIdx.x;                  // 0..255
    int c  = (int)blockIdx.y;
    int w  = (bx & 7) * 32 + (bx >> 3);        // bijective on [0,256); same-XCD w consecutive
    int y0 = w * 4;
    float a0 = apodf(j + 512), a1 = apodf(j + 768), a6 = apodf(j), a7 = apodf(j + 256);
    float ay[4];
    #pragma unroll
    for (int p = 0; p < 4; ++p) ay[p] = apodf(y0 + p);
    float rA[4][4];
    #pragma unroll
    for (int p = 0; p < 4; ++p) {
        const float* rp = img + ((size_t)c * NPIXD + y0 + p) * NPIXD;
        rA[p][0] = rp[j + 512]; rA[p][1] = rp[j + 768];
        rA[p][2] = rp[j];       rA[p][3] = rp[j + 256];
    }
    #pragma unroll
    for (int q = 0; q < 2; ++q) {
        int pa = 2 * q, pb = 2 * q + 1;
        float ay1 = ay[pa], ay2 = ay[pb];
        float2 x0 = make_float2(rA[pa][0] * a0 * ay1, rA[pb][0] * a0 * ay2);
        float2 x1 = make_float2(rA[pa][1] * a1 * ay1, rA[pb][1] * a1 * ay2);
        float2 x6 = make_float2(rA[pa][2] * a6 * ay1, rA[pb][2] * a6 * ay2);
        float2 x7 = make_float2(rA[pa][3] * a7 * ay1, rA[pb][3] * a7 * ay2);
        __syncthreads();                     // buf free (prev epilogue reads done)
        stage0_ip(x0, x1, x6, x7, buf);
        __syncthreads();
        r8_ip(buf, 8);
        __syncthreads();
        r8_ip(buf, 64);
        __syncthreads();
        r4_final_ip(buf);
        __syncthreads();
        // Hermitian unpair epilogue -> stage (half2 bits, scaled 2^22)
        #pragma unroll
        for (int t = 0; t < 2; ++t) {
            int kx = j + t * 256;
            if (kx < KXROWS) {
                float2 Z  = buf[IDX(kx)];
                float2 Zm = buf[IDX((GD - kx) & (GD - 1))];
                __half2 h1 = __floats2half2_rn(0.5f*(Z.x+Zm.x)*FIN_SCALE, 0.5f*(Z.y-Zm.y)*FIN_SCALE);
                __half2 h2 = __floats2half2_rn(0.5f*(Z.y+Zm.y)*FIN_SCALE, 0.5f*(Zm.x-Z.x)*FIN_SCALE);
                stg[kx * 5 + pa] = *reinterpret_cast<unsigned int*>(&h1);
                stg[kx * 5 + pb] = *reinterpret_cast<unsigned int*>(&h2);
            }
        }
    }
    __syncthreads();
    // write-out: one 16B chunk (4 half2 = rows y0..y0+3) per kx
    #pragma unroll
    for (int k = 0; k < 2; ++k) {
        int kx = j + 256 * k;
        if (kx < KXROWS) {
            unsigned int* dst = FinU + ((size_t)c * KXROWS + kx) * FINP + y0;
            const unsigned int* s = &stg[kx * 5];
            *reinterpret_cast<uint4*>(dst) = make_uint4(s[0], s[1], s[2], s[3]);
        }
    }
}

// ---------------- pass 2: col FFTs from half2 Fin; Re -> half4 interleaved --------------
__global__ __launch_bounds__(256) void fft_cols(const unsigned int* __restrict__ FinU,
                                                __half* __restrict__ FhH,
                                                float* __restrict__ FhIm,
                                                int writeIm) {
    __shared__ float2 buf[2176];
    int j = (int)threadIdx.x;
    int kx = blockIdx.x, c = blockIdx.y;
    const unsigned int* inr = FinU + ((size_t)c * KXROWS + kx) * FINP;
    unsigned int u0 = inr[j + 512], u1 = inr[j + 768], u6 = inr[j], u7 = inr[j + 256];
    float2 x0 = __half22float2(*reinterpret_cast<__half2*>(&u0));
    float2 x1 = __half22float2(*reinterpret_cast<__half2*>(&u1));
    float2 x6 = __half22float2(*reinterpret_cast<__half2*>(&u6));
    float2 x7 = __half22float2(*reinterpret_cast<__half2*>(&u7));
    stage0_ip(x0, x1, x6, x7, buf);
    __syncthreads();
    r8_ip(buf, 8);
    __syncthreads();
    r8_ip(buf, 64);
    __syncthreads();
    r4_final_ip(buf);
    __syncthreads();
    // centered packing: n<416 -> pos n+416 (y=n); n>=1632 -> pos n-1632 (y=n-2048)
    __half* basep = FhH + ((size_t)kx * YPACK) * NCHAND + c;
    float*  imb   = FhIm + ((size_t)c * KXROWS + kx) * YPACK;
    for (int n = j; n < GD; n += 256) {
        int pos = -1;
        if (n < 416)         pos = n + 416;
        else if (n >= 1632)  pos = n - 1632;
        if (pos >= 0) {
            float2 z = buf[IDX(n)];
            basep[(size_t)pos * NCHAND] = __float2half_rn(z.x * FIN_TO_FH);
            if (writeIm) imb[pos] = z.y * FIN_TO_IM;
        }
    }
}

// ---------------- Kaiser-Bessel weights ----------------
__device__ __forceinline__ float i0f(float x) {
    float ax = fabsf(x);
    if (ax <= 3.75f) {
        float ts = ax / 3.75f; ts *= ts;
        return 1.0f + ts * (3.5156229f + ts * (3.0899424f + ts * (1.2067492f +
                     ts * (0.2659732f + ts * (0.0360768f + ts * 0.0045813f)))));
    } else {
        float t = 3.75f / ax;
        return expf(ax) / sqrtf(ax) *
               (0.39894228f + t * (0.01328592f + t * (0.00225319f + t * (-0.00157565f +
                t * (0.00916281f + t * (-0.02057706f + t * (0.02635537f +
                t * (-0.01647633f + t * 0.00392377f))))))));
    }
}

__device__ __forceinline__ float kbwf(float dist) {
    float r = dist * (2.0f / 6.0f);
    float s = 1.0f - r * r;
    if (s <= 0.0f) return 0.0f;
    return i0f(BETA_F * sqrtf(s)) * (1.0f / 6.0f);
}

// ---------------- gather (r10 gather6): 2 thr/vis, 4x float4 per kx-tap ----------------
__global__ __launch_bounds__(256) void gather6(const float* __restrict__ uu,
                                               const float* __restrict__ vv,
                                               const float4* __restrict__ FhH4,
                                               const float* __restrict__ FhIm,
                                               float* __restrict__ out,
                                               int out_elems, int complexOut) {
    int tid = (int)threadIdx.x;
    int v = tid >> 1, r = tid & 1;
    int gv = blockIdx.x * 128 + v;
    if (gv >= NVISD) return;
    float tx = uu[gv] * SCALE_F;
    float ty = vv[gv] * SCALE_F;
    float fxf = floorf(tx), fyf = floorf(ty);
    int fxi = (int)fxf, fyi = (int)fyf;

    float wx[3]; int kxr[3]; int cjr[3];
    #pragma unroll
    for (int bb = 0; bb < 3; ++bb) {
        int b = r * 3 + bb, o = b - 2;
        wx[bb] = kbwf(tx - fxf - (float)o);
        int ix = (fxi + o) & (GD - 1);
        int cj = (ix > 1024) ? 1 : 0;
        int kx = cj ? (GD - ix) : ix;
        kxr[bb] = min(kx, KXROWS - 1);
        cjr[bb] = cj;
    }
    float wy[6];
    #pragma unroll
    for (int t = 0; t < 6; ++t) wy[t] = kbwf(ty - fyf - (float)(t - 2));

    int p0n = fyi + 414, p0c = 413 - fyi;
    p0n = min(max(p0n, 0), YPACK - 6);
    p0c = min(max(p0c, 0), YPACK - 6);
    int dn = p0n & 1, dc = p0c & 1;
    int f0n = (p0n - dn) >> 1, f0c = (p0c - dc) >> 1;
    float wn8[8], wc8[8];
    #pragma unroll
    for (int w = 0; w < 8; ++w) {
        int tn = w - dn; wn8[w] = (tn >= 0 && tn < 6) ? wy[tn] : 0.0f;
        int tc = w - dc; wc8[w] = (tc >= 0 && tc < 6) ? wy[5 - tc] : 0.0f;
    }

    float s0 = 0.0f, s1 = 0.0f, s2 = 0.0f, s3 = 0.0f;
    #pragma unroll
    for (int bb = 0; bb < 3; ++bb) {
        const float4* rp = FhH4 + (size_t)kxr[bb] * (YPACK / 2);
        bool cj = cjr[bb] != 0;
        int f0 = cj ? f0c : f0n;
        float wxb = wx[bb];
        #pragma unroll
        for (int q = 0; q < 4; ++q) {
            float4 Q = rp[f0 + q];
            float w0 = wxb * (cj ? wc8[2 * q]     : wn8[2 * q]);
            float w1 = wxb * (cj ? wc8[2 * q + 1] : wn8[2 * q + 1]);
            float2 fa = __half22float2(*reinterpret_cast<const __half2*>(&Q.x));
            float2 fb = __half22float2(*reinterpret_cast<const __half2*>(&Q.y));
            float2 fc = __half22float2(*reinterpret_cast<const __half2*>(&Q.z));
            float2 fd = __half22float2(*reinterpret_cast<const __half2*>(&Q.w));
            s0 = fmaf(w0, fa.x, fmaf(w1, fc.x, s0));
            s1 = fmaf(w0, fa.y, fmaf(w1, fc.y, s1));
            s2 = fmaf(w0, fb.x, fmaf(w1, fd.x, s2));
            s3 = fmaf(w0, fb.y, fmaf(w1, fd.y, s3));
        }
    }
    s0 += __shfl_xor(s0, 1);
    s1 += __shfl_xor(s1, 1);
    s2 += __shfl_xor(s2, 1);
    s3 += __shfl_xor(s3, 1);

    if (!complexOut) {
        if (r == 0 && (size_t)3 * NVISD + gv < (size_t)out_elems) {
            out[0 * NVISD + gv] = s0 * FH_ISCALE;
            out[1 * NVISD + gv] = s1 * FH_ISCALE;
            out[2 * NVISD + gv] = s2 * FH_ISCALE;
            out[3 * NVISD + gv] = s3 * FH_ISCALE;
        }
    } else {
        float sr[4] = {s0, s1, s2, s3};
        #pragma unroll
        for (int c = 0; c < NCHAND; ++c) {
            float sy = 0.0f;
            const float* baseI = FhIm + (size_t)c * KXROWS * YPACK;
            #pragma unroll
            for (int bb = 0; bb < 3; ++bb) {
                const float* rp = baseI + (size_t)kxr[bb] * YPACK;
                bool cj = cjr[bb] != 0;
                float wxb = wx[bb];
                #pragma unroll
                for (int a = 0; a < 6; ++a) {
                    int yv = fyi + (a - 2);
                    int pos = cj ? (416 - yv) : (yv + 416);
                    pos = min(max(pos, 0), YPACK - 1);
                    float w = wxb * wy[a];
                    sy = fmaf(cj ? -w : w, rp[pos], sy);
                }
            }
            sy += __shfl_xor(sy, 1);
            size_t oidx = (size_t)c * NVISD + gv;
            if (r == 0 && 2 * oidx + 1 < (size_t)out_elems) {
                out[2 * oidx] = sr[c] * FH_ISCALE;
                out[2 * oidx + 1] = sy;
            }
        }
    }
}

extern "C" void kernel_launch(void* const* d_in, const int* in_sizes, int n_in,
                              void* d_out, int out_size, void* d_ws, size_t ws_size,
                              hipStream_t stream) {
    (void)in_sizes; (void)n_in;
    const float* img = (const float*)d_in[0];
    const float* uu  = (const float*)d_in[1];
    const float* vv  = (const float*)d_in[2];

    const size_t finBytes  = (size_t)NCHAND * KXROWS * FINP * sizeof(unsigned int); // 6.68 MB
    const size_t fhhBytes  = (size_t)KXROWS * YPACK * NCHAND * sizeof(__half);      // 2.72 MB
    const size_t fhimBytes = (size_t)NCHAND * KXROWS * YPACK * sizeof(float);       // 5.43 MB
    const size_t need = finBytes + fhhBytes + fhimBytes;                            // ~14.8 MB

    char* ws = (char*)d_ws;
    unsigned int* FinU = (unsigned int*)ws;
    __half* FhH  = (__half*)(ws + finBytes);
    float*  FhIm = (float*)(ws + finBytes + fhhBytes);

    if (ws_size < need) return;  // diagnostic guard

    int complexOut = (out_size >= 2 * NCHAND * NVISD) ? 1 : 0;

    fft_rows_fused<<<dim3(256, NCHAND), dim3(256), 0, stream>>>(img, FinU);
    fft_cols<<<dim3(KXROWS, NCHAND), dim3(256), 0, stream>>>(FinU, FhH, FhIm, complexOut);
    gather6<<<dim3((NVISD + 127) / 128), dim3(256), 0, stream>>>(
        uu, vv, (const float4*)FhH, FhIm, (float*)d_out, out_size, complexOut);
}

// Round 14
// 48.619 us; speedup vs baseline: 1.2625x; 1.0100x over previous
//
#include <hip/hip_runtime.h>
#include <hip/hip_fp16.h>
#include <math.h>

#define NPIXD 1024
#define GD    2048
#define NCHAND 4
#define NVISD 200000
#define KXROWS 408     // kx rows computed/stored (gather needs <=401; clamped)
#define YPACK  832     // centered packing: pos = y_signed + 416
#define FINP   1024    // Fin row pitch (half2 slots)
#define IDX(i) ((i) + ((i) >> 4))   // LDS pad
#define RSQ2   0.70710678118654752f

#define FH_SCALE   1048576.0f       // 2^20 net scale of FhH
#define FH_ISCALE  (1.0f / 1048576.0f)
#define FIN_SCALE  4194304.0f       // 2^22 scale of Fin (half2)
#define FIN_TO_FH  0.25f            // 2^22 -> 2^20
#define FIN_TO_IM  (1.0f / 4194304.0f)

static constexpr double PI_D = 3.14159265358979323846;
static constexpr float SCALE_F = (float)(1000.0 * 0.005 * PI_D / (180.0 * 3600.0) * 2048.0);
static constexpr float BETA_F  = (float)(2.34 * 6.0);

// inline apodization: for i in [0,1024), arg = beta^2 - (pi*6*(i-512)/2048)^2 >= 173 > 0
__device__ __forceinline__ float apodf(int i) {
    float n  = (float)(i - 512) * (1.0f / 2048.0f);
    float t  = (float)(PI_D * 6.0) * n;
    float arg = BETA_F * BETA_F - t * t;
    float sq = sqrtf(arg);
    float e  = __expf(sq);
    return sq * 2.0f / (e - 1.0f / e);     // sq / sinh(sq)
}

__device__ __forceinline__ float2 cadd(float2 a, float2 b){ return make_float2(a.x+b.x, a.y+b.y); }
__device__ __forceinline__ float2 csub(float2 a, float2 b){ return make_float2(a.x-b.x, a.y-b.y); }
__device__ __forceinline__ float2 cmulf(float2 a, float2 b){ return make_float2(a.x*b.x - a.y*b.y, a.x*b.y + a.y*b.x); }
__device__ __forceinline__ float2 cnegi(float2 a){ return make_float2(a.y, -a.x); }

// twiddle exp(-i*pi*e/1024); e integer-valued <= 1785 (fp32-exact)
__device__ __forceinline__ float2 twf(float e) {
    float s, c;
    __sincosf(e * (float)(-PI_D / 1024.0), &s, &c);
    return make_float2(c, s);
}

// DFT8 with x2..x5 == 0
__device__ __forceinline__ void dft8_sparse(float2 x0, float2 x1, float2 x6, float2 x7,
                                            float2 y[8]) {
    float2 u0 = cadd(x0,x6), u1 = csub(x0,x6), u2 = cadd(x1,x7), u3 = cnegi(csub(x1,x7));
    y[0]=cadd(u0,u2); y[2]=cadd(u1,u3); y[4]=csub(u0,u2); y[6]=csub(u1,u3);
    float2 o0 = x0;
    float2 o1 = make_float2(RSQ2*(x1.x + x1.y), RSQ2*(x1.y - x1.x));
    float2 o2 = make_float2(-x6.y, x6.x);
    float2 o3 = make_float2(RSQ2*(x7.x - x7.y), RSQ2*(x7.y + x7.x));
    float2 v0 = cadd(o0,o2), v1 = csub(o0,o2), v2 = cadd(o1,o3), v3 = cnegi(csub(o1,o3));
    y[1]=cadd(v0,v2); y[3]=cadd(v1,v3); y[5]=csub(v0,v2); y[7]=csub(v1,v3);
}

__device__ __forceinline__ void dft8_full(const float2 x[8], float2 y[8]) {
    float2 e0=cadd(x[0],x[4]), e1=cadd(x[1],x[5]), e2=cadd(x[2],x[6]), e3=cadd(x[3],x[7]);
    float2 o0=csub(x[0],x[4]), o1=csub(x[1],x[5]), o2=csub(x[2],x[6]), o3=csub(x[3],x[7]);
    o1 = make_float2(RSQ2*(o1.x + o1.y), RSQ2*(o1.y - o1.x));
    o2 = cnegi(o2);
    o3 = make_float2(RSQ2*(o3.y - o3.x), -RSQ2*(o3.x + o3.y));
    float2 u0=cadd(e0,e2), u1=csub(e0,e2), u2=cadd(e1,e3), u3=cnegi(csub(e1,e3));
    y[0]=cadd(u0,u2); y[2]=cadd(u1,u3); y[4]=csub(u0,u2); y[6]=csub(u1,u3);
    float2 v0=cadd(o0,o2), v1=csub(o0,o2), v2=cadd(o1,o3), v3=cnegi(csub(o1,o3));
    y[1]=cadd(v0,v2); y[3]=cadd(v1,v3); y[5]=csub(v0,v2); y[7]=csub(v1,v3);
}

// stage 0 (m=1, pm=j): sparse DFT8 from registers -> buf
__device__ __forceinline__ void stage0_ip(float2 x0, float2 x1, float2 x6, float2 x7,
                                          float2* __restrict__ buf) {
    int j = (int)threadIdx.x;
    float2 y[8];
    dft8_sparse(x0, x1, x6, x7, y);
    buf[IDX(8 * j)] = y[0];
    #pragma unroll
    for (int t = 1; t < 8; ++t)
        buf[IDX(8 * j + t)] = cmulf(twf((float)(t * j)), y[t]);
}

// in-place radix-8 Stockham stage: read-all, barrier, write-all. m in {8, 64}
__device__ __forceinline__ void r8_ip(float2* __restrict__ buf, int m) {
    int j = (int)threadIdx.x;
    float2 x[8];
    #pragma unroll
    for (int k = 0; k < 8; ++k) x[k] = buf[IDX(j + 256 * k)];
    __syncthreads();
    float2 y[8];
    dft8_full(x, y);
    int pm = j & ~(m - 1);
    int base = 7 * pm + j;
    buf[IDX(base)] = y[0];
    #pragma unroll
    for (int t = 1; t < 8; ++t)
        buf[IDX(base + t * m)] = cmulf(twf((float)(t * pm)), y[t]);
}

// final radix-4 (m=512, twiddle-free), PRUNED: only t=0 (j) and t=3 (j+1536) written
__device__ __forceinline__ void r4_final_ip(float2* __restrict__ buf) {
    int j = (int)threadIdx.x;
    float2 v[8];
    #pragma unroll
    for (int h = 0; h < 2; ++h) {
        int jj = j + h * 256;
        v[h*4+0] = buf[IDX(jj)];
        v[h*4+1] = buf[IDX(jj + 512)];
        v[h*4+2] = buf[IDX(jj + 1024)];
        v[h*4+3] = buf[IDX(jj + 1536)];
    }
    __syncthreads();
    #pragma unroll
    for (int h = 0; h < 2; ++h) {
        int jj = j + h * 256;
        float2 a = v[h*4], b = v[h*4+1], cc = v[h*4+2], d = v[h*4+3];
        float2 u0 = cadd(a,cc), u1 = csub(a,cc), u2 = cadd(b,d), u3 = cnegi(csub(b,d));
        buf[IDX(jj)]        = cadd(u0,u2);   // t=0
        buf[IDX(jj + 1536)] = csub(u1,u3);   // t=3
    }
}

// ---------------- Kaiser-Bessel weights (used only for table fill) ----------------
__device__ __forceinline__ float i0f(float x) {
    float ax = fabsf(x);
    if (ax <= 3.75f) {
        float ts = ax / 3.75f; ts *= ts;
        return 1.0f + ts * (3.5156229f + ts * (3.0899424f + ts * (1.2067492f +
                     ts * (0.2659732f + ts * (0.0360768f + ts * 0.0045813f)))));
    } else {
        float t = 3.75f / ax;
        return expf(ax) / sqrtf(ax) *
               (0.39894228f + t * (0.01328592f + t * (0.00225319f + t * (-0.00157565f +
                t * (0.00916281f + t * (-0.02057706f + t * (0.02635537f +
                t * (-0.01647633f + t * 0.00392377f))))))));
    }
}

__device__ __forceinline__ float kbwf(float dist) {
    float r = dist * (2.0f / 6.0f);
    float s = 1.0f - r * r;
    if (s <= 0.0f) return 0.0f;
    return i0f(BETA_F * sqrtf(s)) * (1.0f / 6.0f);
}

// ---------------- pass 1 FUSED: 2 CONSECUTIVE row-pairs/block (y0..y0+3), half2 Fin ----
__global__ __launch_bounds__(256) void fft_rows_fused(const float* __restrict__ img,
                                                      unsigned int* __restrict__ FinU) {
    __shared__ float2 buf[2176];
    __shared__ unsigned int stg[KXROWS * 5];   // 4 half2 per kx + pad (pitch 5)
    int j  = (int)threadIdx.x;
    int bx = (int)blockIdx.x;                  // 0..255
    int c  = (int)blockIdx.y;
    int w  = (bx & 7) * 32 + (bx >> 3);        // bijective on [0,256); same-XCD w consecutive
    int y0 = w * 4;
    float a0 = apodf(j + 512), a1 = apodf(j + 768), a6 = apodf(j), a7 = apodf(j + 256);
    float ay[4];
    #pragma unroll
    for (int p = 0; p < 4; ++p) ay[p] = apodf(y0 + p);
    float rA[4][4];
    #pragma unroll
    for (int p = 0; p < 4; ++p) {
        const float* rp = img + ((size_t)c * NPIXD + y0 + p) * NPIXD;
        rA[p][0] = rp[j + 512]; rA[p][1] = rp[j + 768];
        rA[p][2] = rp[j];       rA[p][3] = rp[j + 256];
    }
    #pragma unroll
    for (int q = 0; q < 2; ++q) {
        int pa = 2 * q, pb = 2 * q + 1;
        float ay1 = ay[pa], ay2 = ay[pb];
        float2 x0 = make_float2(rA[pa][0] * a0 * ay1, rA[pb][0] * a0 * ay2);
        float2 x1 = make_float2(rA[pa][1] * a1 * ay1, rA[pb][1] * a1 * ay2);
        float2 x6 = make_float2(rA[pa][2] * a6 * ay1, rA[pb][2] * a6 * ay2);
        float2 x7 = make_float2(rA[pa][3] * a7 * ay1, rA[pb][3] * a7 * ay2);
        __syncthreads();                     // buf free (prev epilogue reads done)
        stage0_ip(x0, x1, x6, x7, buf);
        __syncthreads();
        r8_ip(buf, 8);
        __syncthreads();
        r8_ip(buf, 64);
        __syncthreads();
        r4_final_ip(buf);
        __syncthreads();
        // Hermitian unpair epilogue -> stage (half2 bits, scaled 2^22)
        #pragma unroll
        for (int t = 0; t < 2; ++t) {
            int kx = j + t * 256;
            if (kx < KXROWS) {
                float2 Z  = buf[IDX(kx)];
                float2 Zm = buf[IDX((GD - kx) & (GD - 1))];
                __half2 h1 = __floats2half2_rn(0.5f*(Z.x+Zm.x)*FIN_SCALE, 0.5f*(Z.y-Zm.y)*FIN_SCALE);
                __half2 h2 = __floats2half2_rn(0.5f*(Z.y+Zm.y)*FIN_SCALE, 0.5f*(Zm.x-Z.x)*FIN_SCALE);
                stg[kx * 5 + pa] = *reinterpret_cast<unsigned int*>(&h1);
                stg[kx * 5 + pb] = *reinterpret_cast<unsigned int*>(&h2);
            }
        }
    }
    __syncthreads();
    // write-out: one 16B chunk (4 half2 = rows y0..y0+3) per kx
    #pragma unroll
    for (int k = 0; k < 2; ++k) {
        int kx = j + 256 * k;
        if (kx < KXROWS) {
            unsigned int* dst = FinU + ((size_t)c * KXROWS + kx) * FINP + y0;
            const unsigned int* s = &stg[kx * 5];
            *reinterpret_cast<uint4*>(dst) = make_uint4(s[0], s[1], s[2], s[3]);
        }
    }
}

// ---------------- pass 2: col FFTs from half2 Fin; Re -> half4 interleaved --------------
// Block (0,0) additionally fills the 1025x8 KB-weight lerp table for the gather.
__global__ __launch_bounds__(256) void fft_cols(const unsigned int* __restrict__ FinU,
                                                __half* __restrict__ FhH,
                                                float* __restrict__ FhIm,
                                                float* __restrict__ Wtab,
                                                int writeIm) {
    __shared__ float2 buf[2176];
    int j = (int)threadIdx.x;
    int kx = blockIdx.x, c = blockIdx.y;
    if (kx == 0 && c == 0) {
        for (int i = j; i <= 1024; i += 256) {
            float frac = (float)i * (1.0f / 1024.0f);
            float* rowp = Wtab + (size_t)i * 8;
            #pragma unroll
            for (int o = 0; o < 6; ++o) rowp[o] = kbwf(frac - (float)(o - 2));
            rowp[6] = 0.0f; rowp[7] = 0.0f;
        }
    }
    const unsigned int* inr = FinU + ((size_t)c * KXROWS + kx) * FINP;
    unsigned int u0 = inr[j + 512], u1 = inr[j + 768], u6 = inr[j], u7 = inr[j + 256];
    float2 x0 = __half22float2(*reinterpret_cast<__half2*>(&u0));
    float2 x1 = __half22float2(*reinterpret_cast<__half2*>(&u1));
    float2 x6 = __half22float2(*reinterpret_cast<__half2*>(&u6));
    float2 x7 = __half22float2(*reinterpret_cast<__half2*>(&u7));
    stage0_ip(x0, x1, x6, x7, buf);
    __syncthreads();
    r8_ip(buf, 8);
    __syncthreads();
    r8_ip(buf, 64);
    __syncthreads();
    r4_final_ip(buf);
    __syncthreads();
    // centered packing: n<416 -> pos n+416 (y=n); n>=1632 -> pos n-1632 (y=n-2048)
    __half* basep = FhH + ((size_t)kx * YPACK) * NCHAND + c;
    float*  imb   = FhIm + ((size_t)c * KXROWS + kx) * YPACK;
    for (int n = j; n < GD; n += 256) {
        int pos = -1;
        if (n < 416)         pos = n + 416;
        else if (n >= 1632)  pos = n - 1632;
        if (pos >= 0) {
            float2 z = buf[IDX(n)];
            basep[(size_t)pos * NCHAND] = __float2half_rn(z.x * FIN_TO_FH);
            if (writeIm) imb[pos] = z.y * FIN_TO_IM;
        }
    }
}

// ---- 6-weight lookup with linear interpolation: w6[o] = w(frac - (o-2)) ----
__device__ __forceinline__ void wtab_lookup(const float* __restrict__ Wtab, float frac,
                                            float w6[6]) {
    float fu = frac * 1024.0f;
    int   iu = (int)fu;                 // 0..1023
    float aa = fu - (float)iu;
    const float4* rw = (const float4*)(Wtab + (size_t)iu * 8);
    float4 A0 = rw[0], A1 = rw[1], B0 = rw[2], B1 = rw[3];
    w6[0] = fmaf(aa, B0.x - A0.x, A0.x);
    w6[1] = fmaf(aa, B0.y - A0.y, A0.y);
    w6[2] = fmaf(aa, B0.z - A0.z, A0.z);
    w6[3] = fmaf(aa, B0.w - A0.w, A0.w);
    w6[4] = fmaf(aa, B1.x - A1.x, A1.x);
    w6[5] = fmaf(aa, B1.y - A1.y, A1.y);
}

// ---------------- gather: 2 thr/vis, table weights, 4x float4 per kx-tap ----------------
__global__ __launch_bounds__(256) void gather6(const float* __restrict__ uu,
                                               const float* __restrict__ vv,
                                               const float4* __restrict__ FhH4,
                                               const float* __restrict__ FhIm,
                                               const float* __restrict__ Wtab,
                                               float* __restrict__ out,
                                               int out_elems, int complexOut) {
    int tid = (int)threadIdx.x;
    int v = tid >> 1, r = tid & 1;
    int gv = blockIdx.x * 128 + v;
    if (gv >= NVISD) return;
    float tx = uu[gv] * SCALE_F;
    float ty = vv[gv] * SCALE_F;
    float fxf = floorf(tx), fyf = floorf(ty);
    int fxi = (int)fxf, fyi = (int)fyf;

    float wxf[6], wy[6];
    wtab_lookup(Wtab, tx - fxf, wxf);
    wtab_lookup(Wtab, ty - fyf, wy);

    float wx[3]; int kxr[3]; int cjr[3];
    #pragma unroll
    for (int bb = 0; bb < 3; ++bb) {
        int b = r * 3 + bb, o = b - 2;
        wx[bb] = wxf[b];
        int ix = (fxi + o) & (GD - 1);
        int cj = (ix > 1024) ? 1 : 0;
        int kx = cj ? (GD - ix) : ix;
        kxr[bb] = min(kx, KXROWS - 1);
        cjr[bb] = cj;
    }

    int p0n = fyi + 414, p0c = 413 - fyi;
    p0n = min(max(p0n, 0), YPACK - 6);
    p0c = min(max(p0c, 0), YPACK - 6);
    int dn = p0n & 1, dc = p0c & 1;
    int f0n = (p0n - dn) >> 1, f0c = (p0c - dc) >> 1;
    float wn8[8], wc8[8];
    #pragma unroll
    for (int w = 0; w < 8; ++w) {
        int tn = w - dn; wn8[w] = (tn >= 0 && tn < 6) ? wy[tn] : 0.0f;
        int tc = w - dc; wc8[w] = (tc >= 0 && tc < 6) ? wy[5 - tc] : 0.0f;
    }

    float s0 = 0.0f, s1 = 0.0f, s2 = 0.0f, s3 = 0.0f;
    #pragma unroll
    for (int bb = 0; bb < 3; ++bb) {
        const float4* rp = FhH4 + (size_t)kxr[bb] * (YPACK / 2);
        bool cj = cjr[bb] != 0;
        int f0 = cj ? f0c : f0n;
        float wxb = wx[bb];
        #pragma unroll
        for (int q = 0; q < 4; ++q) {
            float4 Q = rp[f0 + q];
            float w0 = wxb * (cj ? wc8[2 * q]     : wn8[2 * q]);
            float w1 = wxb * (cj ? wc8[2 * q + 1] : wn8[2 * q + 1]);
            float2 fa = __half22float2(*reinterpret_cast<const __half2*>(&Q.x));
            float2 fb = __half22float2(*reinterpret_cast<const __half2*>(&Q.y));
            float2 fc = __half22float2(*reinterpret_cast<const __half2*>(&Q.z));
            float2 fd = __half22float2(*reinterpret_cast<const __half2*>(&Q.w));
            s0 = fmaf(w0, fa.x, fmaf(w1, fc.x, s0));
            s1 = fmaf(w0, fa.y, fmaf(w1, fc.y, s1));
            s2 = fmaf(w0, fb.x, fmaf(w1, fd.x, s2));
            s3 = fmaf(w0, fb.y, fmaf(w1, fd.y, s3));
        }
    }
    s0 += __shfl_xor(s0, 1);
    s1 += __shfl_xor(s1, 1);
    s2 += __shfl_xor(s2, 1);
    s3 += __shfl_xor(s3, 1);

    if (!complexOut) {
        if (r == 0 && (size_t)3 * NVISD + gv < (size_t)out_elems) {
            out[0 * NVISD + gv] = s0 * FH_ISCALE;
            out[1 * NVISD + gv] = s1 * FH_ISCALE;
            out[2 * NVISD + gv] = s2 * FH_ISCALE;
            out[3 * NVISD + gv] = s3 * FH_ISCALE;
        }
    } else {
        float sr[4] = {s0, s1, s2, s3};
        #pragma unroll
        for (int c = 0; c < NCHAND; ++c) {
            float sy = 0.0f;
            const float* baseI = FhIm + (size_t)c * KXROWS * YPACK;
            #pragma unroll
            for (int bb = 0; bb < 3; ++bb) {
                const float* rp = baseI + (size_t)kxr[bb] * YPACK;
                bool cj = cjr[bb] != 0;
                float wxb = wx[bb];
                #pragma unroll
                for (int a = 0; a < 6; ++a) {
                    int yv = fyi + (a - 2);
                    int pos = cj ? (416 - yv) : (yv + 416);
                    pos = min(max(pos, 0), YPACK - 1);
                    float w = wxb * wy[a];
                    sy = fmaf(cj ? -w : w, rp[pos], sy);
                }
            }
            sy += __shfl_xor(sy, 1);
            size_t oidx = (size_t)c * NVISD + gv;
            if (r == 0 && 2 * oidx + 1 < (size_t)out_elems) {
                out[2 * oidx] = sr[c] * FH_ISCALE;
                out[2 * oidx + 1] = sy;
            }
        }
    }
}

extern "C" void kernel_launch(void* const* d_in, const int* in_sizes, int n_in,
                              void* d_out, int out_size, void* d_ws, size_t ws_size,
                              hipStream_t stream) {
    (void)in_sizes; (void)n_in;
    const float* img = (const float*)d_in[0];
    const float* uu  = (const float*)d_in[1];
    const float* vv  = (const float*)d_in[2];

    const size_t finBytes  = (size_t)NCHAND * KXROWS * FINP * sizeof(unsigned int); // 6.68 MB
    const size_t fhhBytes  = (size_t)KXROWS * YPACK * NCHAND * sizeof(__half);      // 2.72 MB
    const size_t fhimBytes = (size_t)NCHAND * KXROWS * YPACK * sizeof(float);       // 5.43 MB
    const size_t wtabBytes = 1025 * 8 * sizeof(float);                              // 32.8 KB
    const size_t need = finBytes + fhhBytes + fhimBytes + wtabBytes;                // ~14.9 MB

    char* ws = (char*)d_ws;
    unsigned int* FinU = (unsigned int*)ws;
    __half* FhH  = (__half*)(ws + finBytes);
    float*  FhIm = (float*)(ws + finBytes + fhhBytes);
    float*  Wtab = (float*)(ws + finBytes + fhhBytes + fhimBytes);

    if (ws_size < need) return;  // diagnostic guard

    int complexOut = (out_size >= 2 * NCHAND * NVISD) ? 1 : 0;

    fft_rows_fused<<<dim3(256, NCHAND), dim3(256), 0, stream>>>(img, FinU);
    fft_cols<<<dim3(KXROWS, NCHAND), dim3(256), 0, stream>>>(FinU, FhH, FhIm, Wtab, complexOut);
    gather6<<<dim3((NVISD + 127) / 128), dim3(256), 0, stream>>>(
        uu, vv, (const float4*)FhH, FhIm, Wtab, (float*)d_out, out_size, complexOut);
}